// Round 12
// baseline (759.506 us; speedup 1.0000x reference)
//
#include <hip/hip_runtime.h>

typedef float  v2f    __attribute__((ext_vector_type(2)));
typedef float  f32x4  __attribute__((ext_vector_type(4)));
typedef __bf16 bf16x8 __attribute__((ext_vector_type(8)));
typedef __bf16 bf16x4 __attribute__((ext_vector_type(4)));
typedef unsigned int u32x4a4 __attribute__((ext_vector_type(4), aligned(4)));

constexpr int XC = 224, HFWD = 64, U = 128, RR = 16, VW = 192;
#define BLOCK 256
constexpr int H1_PL = RR * 128;

static __device__ __forceinline__ f32x4 mfma16(bf16x8 a, bf16x8 b, f32x4 c) {
    return __builtin_amdgcn_mfma_f32_16x16x32_bf16(a, b, c, 0, 0, 0);
}
static __device__ __forceinline__ void split(float v, __bf16& h, __bf16& l) {
    h = (__bf16)v; l = (__bf16)(v - (float)h);
}
static __device__ __forceinline__ unsigned short bfb(__bf16 b) {
    return __builtin_bit_cast(unsigned short, b);
}
static __device__ __forceinline__ __bf16 bbf(unsigned short u) {
    return __builtin_bit_cast(__bf16, u);
}
static __device__ __forceinline__ bf16x8 ldv(const __bf16* p) {   // 4B-aligned 16B load
    return __builtin_bit_cast(bf16x8, *(const u32x4a4*)p);
}

// ---------------- prepass: split x[:,32:224] into bf16 h/l planes ----------------
extern "C" __global__ __launch_bounds__(256)
void vsplit(const float* __restrict__ x, __bf16* __restrict__ vh,
            __bf16* __restrict__ vl, int B)
{
    int idx = blockIdx.x * 256 + threadIdx.x;
    int row = idx / 24, c8 = (idx - row * 24) * 8;
    if (row >= B) return;
    const float* p = x + (long)row * XC + 32 + c8;
    bf16x8 h, l;
    #pragma unroll
    for (int j = 0; j < 8; ++j) { __bf16 hh, ll; split(p[j], hh, ll); h[j] = hh; l[j] = ll; }
    *(bf16x8*)(vh + (long)row * VW + c8) = h;
    *(bf16x8*)(vl + (long)row * VW + c8) = l;
}

// ---------------- main kernel ----------------
// 4 waves/block; wave g owns neurons [32g,32g+32) for all 16 rows. lane: lr=l&15
// (batch row / B-col), lg=l>>4 (k-group). A = W^T register-resident (split bf16);
// recurrent buf register-resident. C/D: col=l&15 (row), row=(l>>4)*4+reg (neuron).
// V7: L2 uses 6 independent MFMA chains (depth 2); aux chains init via zero4/bias
// C-operand; h1 fragments read upfront after barrier 1.
template<int PS>
__global__ __launch_bounds__(BLOCK, 2)
void rmlp_v7(const float* __restrict__ x,  const __bf16* __restrict__ vh,
             const __bf16* __restrict__ vl,
             const float* __restrict__ W1, const float* __restrict__ b1,
             const float* __restrict__ W2, const float* __restrict__ b2,
             const float* __restrict__ W3, const float* __restrict__ b3,
             float* __restrict__ out)
{
    __shared__ __bf16 h1h[H1_PL], h1l[H1_PL];
    __shared__ float  parts[64];

    const int t  = threadIdx.x;
    const int g  = t >> 6, l = t & 63;
    const int lr = l & 15, lg = l >> 4;
    const long row0 = (long)blockIdx.x * RR;

    // ---- A-fragments (weights, split bf16) -> registers, once ----
    bf16x8 a1h[2][3], a1l[2][3], a2h[2][4], a2l[2][4];
    #pragma unroll
    for (int t_ = 0; t_ < 2; ++t_) {
        const int n = g * 32 + t_ * 16 + lr;
        #pragma unroll
        for (int ks = 0; ks < 3; ++ks)
            #pragma unroll
            for (int j = 0; j < 8; ++j) {
                float v = W1[(ks * 32 + lg * 8 + j) * U + n];
                __bf16 h, lo; split(v, h, lo);
                a1h[t_][ks][j] = h; a1l[t_][ks][j] = lo;
            }
        #pragma unroll
        for (int ks = 0; ks < 4; ++ks)
            #pragma unroll
            for (int j = 0; j < 8; ++j) {
                float v = W2[(ks * 32 + lg * 8 + j) * U + n];
                __bf16 h, lo; split(v, h, lo);
                a2h[t_][ks][j] = h; a2l[t_][ks][j] = lo;
            }
    }
    // ---- per-lane vectors: n(t_,q) = 32g + 16t_ + 4lg + q matches C-frag rows ----
    f32x4 b1q[2], w196q[2], b2q[2], w3q[2];
    #pragma unroll
    for (int t_ = 0; t_ < 2; ++t_)
        #pragma unroll
        for (int q = 0; q < 4; ++q) {
            int n = g * 32 + t_ * 16 + lg * 4 + q;
            b1q[t_][q]   = b1[n];
            w196q[t_][q] = W1[96 * U + n];
            b2q[t_][q]   = b2[n];
            w3q[t_][q]   = W3[n];
        }
    const float b3s = b3[0];
    const f32x4 zero4 = {0.f, 0.f, 0.f, 0.f};

    // ---- buf (recurrent window) -> registers: e = x[row lr, lg*8 .. +7] ----
    bf16x8 Bbh, Bbl;
    {
        const float* pe = x + (row0 + lr) * XC + lg * 8;
        #pragma unroll
        for (int q = 0; q < 4; ++q) {
            v2f e = *(const v2f*)(pe + 2 * q);
            __bf16 h, lo;
            split(e[0], h, lo); Bbh[2 * q]     = h; Bbl[2 * q]     = lo;
            split(e[1], h, lo); Bbh[2 * q + 1] = h; Bbl[2 * q + 1] = lo;
        }
    }
    const float* xrow  = x + (row0 + lr) * XC;
    const __bf16* pvh  = PS ? vh + (row0 + lr) * VW + lg * 8 : nullptr;
    const __bf16* pvl  = PS ? vl + (row0 + lr) * VW + lg * 8 : nullptr;
    const int    h1swz = (lr & 7) << 3;

    auto LOADF = [&](int i, bf16x8& h0, bf16x8& l0, bf16x8& h1f, bf16x8& l1f) {
        if (PS) {
            h0  = ldv(pvh + 2 * i);        l0  = ldv(pvl + 2 * i);
            h1f = ldv(pvh + 2 * i + 32);   l1f = ldv(pvl + 2 * i + 32);
        } else {
            const float* p0 = xrow + 32 + 2 * i + lg * 8;
            #pragma unroll
            for (int q = 0; q < 4; ++q) {
                v2f d = *(const v2f*)(p0 + 2 * q);
                __bf16 h, lo;
                split(d[0], h, lo); h0[2 * q]     = h; l0[2 * q]     = lo;
                split(d[1], h, lo); h0[2 * q + 1] = h; l0[2 * q + 1] = lo;
            }
            #pragma unroll
            for (int q = 0; q < 4; ++q) {
                v2f d = *(const v2f*)(p0 + 32 + 2 * q);
                __bf16 h, lo;
                split(d[0], h, lo); h1f[2 * q]     = h; l1f[2 * q]     = lo;
                split(d[1], h, lo); h1f[2 * q + 1] = h; l1f[2 * q + 1] = lo;
            }
        }
    };

    bf16x8 cvh0, cvl0, cvh1, cvl1;
    LOADF(0, cvh0, cvl0, cvh1, cvl1);

    for (int i = 0; i < HFWD; ++i) {
        const float fi = (float)i;
        // ========== layer 1: K=96, 3 chains (v-tiles first; buf tile last) ==========
        f32x4 c0[2], c1[2], c2[2];
        #pragma unroll
        for (int t_ = 0; t_ < 2; ++t_) {
            #pragma unroll
            for (int q = 0; q < 4; ++q)
                c0[t_][q] = fmaf(fi, w196q[t_][q], b1q[t_][q]);
            c0[t_] = mfma16(a1h[t_][1], cvh0, c0[t_]);
            c1[t_] = mfma16(a1h[t_][1], cvl0, zero4);     // init-by-mfma
            c2[t_] = mfma16(a1l[t_][1], cvh0, zero4);     // init-by-mfma
            c0[t_] = mfma16(a1h[t_][2], cvh1, c0[t_]);
            c1[t_] = mfma16(a1h[t_][2], cvl1, c1[t_]);
            c2[t_] = mfma16(a1l[t_][2], cvh1, c2[t_]);
        }
        // prefetch next step's v fragments
        bf16x8 nvh0, nvl0, nvh1, nvl1;
        LOADF(i + 1, nvh0, nvl0, nvh1, nvl1);

        // buf tile (kstep 0)
        #pragma unroll
        for (int t_ = 0; t_ < 2; ++t_) {
            c0[t_] = mfma16(a1h[t_][0], Bbh, c0[t_]);
            c1[t_] = mfma16(a1h[t_][0], Bbl, c1[t_]);
            c2[t_] = mfma16(a1l[t_][0], Bbh, c2[t_]);
        }
        // epilogue: combine + relu + split + store h1
        #pragma unroll
        for (int t_ = 0; t_ < 2; ++t_) {
            bf16x4 hh, ll;
            #pragma unroll
            for (int q = 0; q < 4; ++q) {
                float v = fmaxf(c0[t_][q] + c1[t_][q] + c2[t_][q], 0.0f);
                __bf16 h, lo; split(v, h, lo);
                hh[q] = h; ll[q] = lo;
            }
            int o = (lr * 128 + g * 32 + t_ * 16 + lg * 4) ^ h1swz;
            *(bf16x4*)(h1h + o) = hh;
            *(bf16x4*)(h1l + o) = ll;
        }
        __syncthreads();   // barrier 1: h1 complete

        // ========== layer 2: K=128, 6 independent chains (depth 2) ==========
        // read all fragments upfront so ds latency overlaps first MFMAs
        bf16x8 Hh[4], Hl[4];
        #pragma unroll
        for (int ks = 0; ks < 4; ++ks) {
            int o = (lr * 128 + ks * 32 + lg * 8) ^ h1swz;
            Hh[ks] = *(const bf16x8*)(h1h + o);
            Hl[ks] = *(const bf16x8*)(h1l + o);
        }
        f32x4 dA[2], dB[2], dC[2], dD[2], dE[2], dF[2];
        #pragma unroll
        for (int t_ = 0; t_ < 2; ++t_) {
            dA[t_] = mfma16(a2h[t_][0], Hh[0], b2q[t_]);   // main chain carries bias
            dB[t_] = mfma16(a2h[t_][1], Hh[1], zero4);
            dC[t_] = mfma16(a2h[t_][0], Hl[0], zero4);
            dD[t_] = mfma16(a2h[t_][1], Hl[1], zero4);
            dE[t_] = mfma16(a2l[t_][0], Hh[0], zero4);
            dF[t_] = mfma16(a2l[t_][1], Hh[1], zero4);
            dA[t_] = mfma16(a2h[t_][2], Hh[2], dA[t_]);
            dB[t_] = mfma16(a2h[t_][3], Hh[3], dB[t_]);
            dC[t_] = mfma16(a2h[t_][2], Hl[2], dC[t_]);
            dD[t_] = mfma16(a2h[t_][3], Hl[3], dD[t_]);
            dE[t_] = mfma16(a2l[t_][2], Hh[2], dE[t_]);
            dF[t_] = mfma16(a2l[t_][3], Hh[3], dF[t_]);
        }
        // ========== layer 3 ==========
        float p = 0.0f;
        #pragma unroll
        for (int t_ = 0; t_ < 2; ++t_)
            #pragma unroll
            for (int q = 0; q < 4; ++q) {
                float h2 = (dA[t_][q] + dB[t_][q]) + (dC[t_][q] + dD[t_][q])
                         + (dE[t_][q] + dF[t_][q]);
                p = fmaf(fmaxf(h2, 0.0f), w3q[t_][q], p);
            }
        p += __shfl_xor(p, 16, 64);
        p += __shfl_xor(p, 32, 64);
        if (l < 16) parts[g * 16 + lr] = p;
        __syncthreads();   // barrier 2: partials ready

        const float s = b3s + parts[lr] + parts[16 + lr] + parts[32 + lr] + parts[48 + lr];
        if (t < 16) out[(row0 + t) * HFWD + i] = s;

        // buf register shift: buf[k] = buf[k+1], buf[31] = s
        {
            unsigned int packed = ((unsigned int)bfb(Bbh[0]) << 16) | bfb(Bbl[0]);
            unsigned int up = (unsigned int)__shfl((int)packed, (l + 16) & 63, 64);
            #pragma unroll
            for (int j = 0; j < 7; ++j) { Bbh[j] = Bbh[j + 1]; Bbl[j] = Bbl[j + 1]; }
            if (lg == 3) {
                __bf16 h, lo; split(s, h, lo);
                Bbh[7] = h; Bbl[7] = lo;
            } else {
                Bbh[7] = bbf((unsigned short)(up >> 16));
                Bbl[7] = bbf((unsigned short)(up & 0xffffu));
            }
        }
        cvh0 = nvh0; cvl0 = nvl0; cvh1 = nvh1; cvl1 = nvl1;
    }
}

extern "C" void kernel_launch(void* const* d_in, const int* in_sizes, int n_in,
                              void* d_out, int out_size, void* d_ws, size_t ws_size,
                              hipStream_t stream) {
    const float* x  = (const float*)d_in[0];
    const float* W1 = (const float*)d_in[1];
    const float* b1 = (const float*)d_in[2];
    const float* W2 = (const float*)d_in[3];
    const float* b2 = (const float*)d_in[4];
    const float* W3 = (const float*)d_in[5];
    const float* b3 = (const float*)d_in[6];
    float* out = (float*)d_out;

    const int B    = in_sizes[0] / XC;   // 65536
    const int nblk = B / RR;             // 4096
    const size_t plane = (size_t)B * VW * sizeof(__bf16);   // 25.2 MB
    const size_t need  = 2 * plane;                         // 50.3 MB

    if (ws_size >= need) {
        __bf16* vh = (__bf16*)d_ws;
        __bf16* vl = vh + (size_t)B * VW;
        vsplit<<<(B * 24 + 255) / 256, 256, 0, stream>>>(x, vh, vl, B);
        rmlp_v7<1><<<nblk, BLOCK, 0, stream>>>(x, vh, vl, W1, b1, W2, b2, W3, b3, out);
    } else {
        rmlp_v7<0><<<nblk, BLOCK, 0, stream>>>(x, nullptr, nullptr, W1, b1, W2, b2, W3, b3, out);
    }
}